// Round 1
// 438.358 us; speedup vs baseline: 1.1033x; 1.1033x over previous
//
#include <hip/hip_runtime.h>
#include <math.h>

// Problem constants (fixed by the reference file).
constexpr int N_NODES = 100000;
constexpr int N_EDGES = 3200000;
constexpr int F_IN    = 512;
constexpr int HID     = 16;   // HIDDEN == N_CLASSES == 16

constexpr int NPAD = 100352;  // N_NODES rounded up (words)

// Binning parameters: bucket = dst >> 8 (256 nodes/bucket)
constexpr int B_BITS = 8;
constexpr int NPB    = 1 << B_BITS;                    // 256 nodes per bucket
constexpr int NBKT   = (N_NODES + NPB - 1) / NPB;      // 391 buckets
constexpr int SBLK   = 400;                            // scatter blocks
constexpr int CHUNK  = N_EDGES / SBLK;                 // 8000 edges/block (exact)
// Capacity-slotted buckets: mean 8192 edges + <=768 pad, sd ~90 -> 12 sigma margin.
constexpr int CAP    = 10240;                          // slots per bucket (mult of 4)

typedef float f32x4 __attribute__((ext_vector_type(4)));
typedef short bfrag8 __attribute__((ext_vector_type(8)));   // 8 bf16 (4 VGPRs)

__device__ __forceinline__ unsigned short f2bf_rne(float f) {
    unsigned int u = __float_as_uint(f);
    u += 0x7FFFu + ((u >> 16) & 1u);   // round-to-nearest-even
    return (unsigned short)(u >> 16);
}
__device__ __forceinline__ float bf2f(unsigned short u) {
    return __uint_as_float((unsigned int)u << 16);
}

// ---------------------------------------------------------------------------
// K0: prep — W1 transpose->bf16, gcur init to slotted bases, sentinel rows = 0.
__global__ __launch_bounds__(256) void prep_kernel(const float* __restrict__ W1,
                                                   unsigned short* __restrict__ w1t,
                                                   int* __restrict__ gcur,
                                                   unsigned short* __restrict__ hh_bf,
                                                   unsigned short* __restrict__ hh2_bf) {
    int i = blockIdx.x * 256 + threadIdx.x;
    if (i < F_IN * HID) {
        int k = i >> 4, n = i & 15;
        w1t[n * F_IN + k] = f2bf_rne(W1[i]);
    }
    if (i < NBKT) gcur[i] = i * CAP;
    if (i < 16) {                       // sentinel row N_NODES reads as zero
        hh_bf [N_NODES * 16 + i] = 0;
        hh2_bf[N_NODES * 16 + i] = 0;
    }
}

// ---------------------------------------------------------------------------
// K1: scatter edges into capacity-slotted bucket array (no count/scan passes).
// Stages the chunk in LDS so src/dst are read from HBM exactly once.
// Packed as (local_dst<<24 | src).
__global__ __launch_bounds__(1024) void bin_scatter_kernel(const int* __restrict__ src,
                                                           const int* __restrict__ dst,
                                                           int* __restrict__ gcur,
                                                           unsigned int* __restrict__ binned) {
    __shared__ int sdst[CHUNK];
    __shared__ int ssrc[CHUNK];
    __shared__ int cnt[NBKT];
    __shared__ int cur[NBKT];
    const int tid = threadIdx.x;
    for (int t = tid; t < NBKT; t += 1024) cnt[t] = 0;
    const int base = blockIdx.x * CHUNK;
    for (int i = tid; i < CHUNK; i += 1024) {
        sdst[i] = dst[base + i];
        ssrc[i] = src[base + i];
    }
    __syncthreads();
    for (int i = tid; i < CHUNK; i += 1024)
        atomicAdd(&cnt[sdst[i] >> B_BITS], 1);
    __syncthreads();
    for (int t = tid; t < NBKT; t += 1024)
        cur[t] = cnt[t] ? atomicAdd(&gcur[t], cnt[t]) : 0;
    __syncthreads();
    for (int i = tid; i < CHUNK; i += 1024) {
        int d = sdst[i];
        int b = d >> B_BITS;
        int pos = atomicAdd(&cur[b], 1);
        binned[pos] = ((unsigned)(d & (NPB - 1)) << 24) | (unsigned)ssrc[i];
    }
}

// ---------------------------------------------------------------------------
// K2: one block per bucket: LDS CSR build with per-node 4-alignment padding
// (sentinel src = N_NODES fills pad slots -> pull loops need no tail handling,
// and csr starts are 16B aligned for int4 loads). Emits row/rowe/dinv.
__global__ __launch_bounds__(1024) void csr_bucket_kernel(const unsigned int* __restrict__ binned,
                                                          const int* __restrict__ gcur,
                                                          int* __restrict__ row,
                                                          int* __restrict__ rowe,
                                                          int* __restrict__ csr,
                                                          float* __restrict__ dinv) {
    __shared__ unsigned int eb[CAP];   // 40 KB
    __shared__ int deg[NPB];
    __shared__ int pre[NPB];
    __shared__ int cur[NPB];
    const int tid = threadIdx.x;
    const int b = blockIdx.x;
    const int e0 = b * CAP;
    int ne = gcur[b] - e0;
    if (ne > CAP) ne = CAP;            // safety (statistically impossible)
    if (ne < 0) ne = 0;

    if (tid < NPB) deg[tid] = 0;
    for (int i = tid; i < ne; i += 1024) eb[i] = binned[e0 + i];
    __syncthreads();
    for (int i = tid; i < ne; i += 1024)
        atomicAdd(&deg[eb[i] >> 24], 1);
    __syncthreads();
    if (tid < NPB) pre[tid] = (deg[tid] + 3) & ~3;   // padded degree
    __syncthreads();
    for (int off = 1; off < NPB; off <<= 1) {
        int v = 0;
        if (tid < NPB && tid >= off) v = pre[tid - off];
        __syncthreads();
        if (tid < NPB) pre[tid] += v;
        __syncthreads();
    }
    if (tid < NPB) {
        int excl = (tid == 0) ? 0 : pre[tid - 1];
        int start = e0 + excl;
        cur[tid] = start;
        int node = b * NPB + tid;
        if (node < N_NODES) {
            int pd = (deg[tid] + 3) & ~3;
            row[node]  = start;
            rowe[node] = start + pd;
            dinv[node] = rsqrtf((float)deg[tid] + 1.0f);
        }
    }
    __syncthreads();
    for (int i = tid; i < ne; i += 1024) {
        unsigned int v = eb[i];
        int pos = atomicAdd(&cur[v >> 24], 1);
        csr[pos] = (int)(v & 0xFFFFFFu);
    }
    // sentinel fill of pad slots (disjoint range from the scatter above)
    if (tid < NPB) {
        int node = b * NPB + tid;
        if (node < N_NODES) {
            int d = deg[tid];
            int pd = (d + 3) & ~3;
            int s = e0 + ((tid == 0) ? 0 : pre[tid - 1]) + d;
            for (int q = d; q < pd; ++q) csr[s++] = N_NODES;
        }
    }
}

// ---------------------------------------------------------------------------
// K3: GEMM1 via MFMA bf16, NO LDS, NO barrier (unchanged from 483us version).
__global__ __launch_bounds__(256) void gemm1_kernel(const float* __restrict__ x,
                                                    const unsigned short* __restrict__ w1t,
                                                    const float* __restrict__ b1,
                                                    const float* __restrict__ dinv,
                                                    unsigned short* __restrict__ hh_bf,
                                                    float* __restrict__ aggs1) {
    const int tid  = threadIdx.x;
    const int lane = tid & 63;
    const int wv   = tid >> 6;
    const int m    = lane & 15;
    const int quad = lane >> 4;
    const int node0 = blockIdx.x * 64 + wv * 16;   // this wave's 16-node tile

    int gm = node0 + m; if (gm >= N_NODES) gm = N_NODES - 1;  // clamp loads
    const float* arow = x + (size_t)gm * F_IN + quad * 8;

    // preload all 16 B-frags (16 KB table, L2-hot)
    bfrag8 bfr[16];
    const unsigned short* wbase = w1t + m * F_IN + quad * 8;
    #pragma unroll
    for (int t = 0; t < 16; ++t)
        bfr[t] = *(const bfrag8*)(wbase + t * 32);

    f32x4 acc = {0.f, 0.f, 0.f, 0.f};
    #pragma unroll 4
    for (int t = 0; t < 16; ++t) {
        float4 lo = *(const float4*)(arow + t * 32);
        float4 hi = *(const float4*)(arow + t * 32 + 4);
        bfrag8 afr;
        afr[0] = (short)f2bf_rne(lo.x); afr[1] = (short)f2bf_rne(lo.y);
        afr[2] = (short)f2bf_rne(lo.z); afr[3] = (short)f2bf_rne(lo.w);
        afr[4] = (short)f2bf_rne(hi.x); afr[5] = (short)f2bf_rne(hi.y);
        afr[6] = (short)f2bf_rne(hi.z); afr[7] = (short)f2bf_rne(hi.w);
        acc = __builtin_amdgcn_mfma_f32_16x16x32_bf16(afr, bfr[t], acc, 0, 0, 0);
    }

    // epilogue: D[row=quad*4+r][col=m] (verified mapping)
    const float b1j = b1[m];
    #pragma unroll
    for (int r = 0; r < 4; ++r) {
        int gn = node0 + quad * 4 + r;
        if (gn < N_NODES) {
            float dv = dinv[gn];
            float hv = acc[r] * dv;
            size_t o = (size_t)gn * 16 + m;
            hh_bf[o] = f2bf_rne(hv);
            aggs1[o] = hv * dv + b1j;
        }
    }
}

// ---------------------------------------------------------------------------
// K4: pull1 + relu + layer2 fused. 4 lanes per node, each owning 4 features.
// Per 4 edges: one aligned int4 csr load + four dwordx2 (ushort4) gathers per
// lane — ~6x fewer memory instructions than the 16-lane/ushort version.
__global__ __launch_bounds__(256) void pull1_kernel(const unsigned short* __restrict__ hh_bf,
                                                    const float* __restrict__ aggs1,
                                                    const float* __restrict__ dinv,
                                                    const int* __restrict__ row,
                                                    const int* __restrict__ rowe,
                                                    const int* __restrict__ csr,
                                                    const float* __restrict__ W2,
                                                    const float* __restrict__ b2,
                                                    unsigned short* __restrict__ hh2_bf,
                                                    float* __restrict__ aggs2) {
    __shared__ f32x4 w2s[64];   // W2 row-major [16][16] as float4[64]
    __shared__ f32x4 b2s[4];
    const int tid = threadIdx.x;
    if (tid < 64) w2s[tid] = ((const f32x4*)W2)[tid];
    if (tid < 4)  b2s[tid] = ((const f32x4*)b2)[tid];
    __syncthreads();

    int t = blockIdx.x * 256 + tid;
    int node = t >> 2;
    int l = t & 3;                      // feature quad: features 4l..4l+3
    if (node >= N_NODES) return;

    int p = row[node], e = rowe[node];
    const unsigned short* hb = hh_bf + (l << 2);
    f32x4 a0 = {0,0,0,0}, a1 = {0,0,0,0}, a2 = {0,0,0,0}, a3 = {0,0,0,0};
    for (; p < e; p += 4) {
        int4 s = *(const int4*)(csr + p);          // aligned: starts are mult-of-4
        ushort4 g0 = *(const ushort4*)(hb + (s.x << 4));
        ushort4 g1 = *(const ushort4*)(hb + (s.y << 4));
        ushort4 g2 = *(const ushort4*)(hb + (s.z << 4));
        ushort4 g3 = *(const ushort4*)(hb + (s.w << 4));
        a0.x += bf2f(g0.x); a0.y += bf2f(g0.y); a0.z += bf2f(g0.z); a0.w += bf2f(g0.w);
        a1.x += bf2f(g1.x); a1.y += bf2f(g1.y); a1.z += bf2f(g1.z); a1.w += bf2f(g1.w);
        a2.x += bf2f(g2.x); a2.y += bf2f(g2.y); a2.z += bf2f(g2.z); a2.w += bf2f(g2.w);
        a3.x += bf2f(g3.x); a3.y += bf2f(g3.y); a3.z += bf2f(g3.z); a3.w += bf2f(g3.w);
    }
    f32x4 a = (a0 + a1) + (a2 + a3);
    float dv = dinv[node];
    f32x4 base = *(const f32x4*)(aggs1 + ((size_t)node << 4) + (l << 2));
    float v[4];
    #pragma unroll
    for (int c = 0; c < 4; ++c) v[c] = fmaxf(base[c] + dv * a[c], 0.f);  // relu(h1)

    // h2[4l+d] = sum_k v_node[k] * W2[k][4l+d]; v[c] lives on lane k>>2 at c=k&3
    f32x4 h2 = {0.f, 0.f, 0.f, 0.f};
    #pragma unroll
    for (int k = 0; k < 16; ++k) {
        float vk = __shfl(v[k & 3], k >> 2, 4);
        f32x4 w = w2s[k * 4 + l];
        h2.x += vk * w.x; h2.y += vk * w.y; h2.z += vk * w.z; h2.w += vk * w.w;
    }
    f32x4 bb = b2s[l];
    ushort4 hs;
    f32x4 ag;
    float hv0 = h2.x * dv; hs.x = f2bf_rne(hv0); ag.x = hv0 * dv + bb.x;
    float hv1 = h2.y * dv; hs.y = f2bf_rne(hv1); ag.y = hv1 * dv + bb.y;
    float hv2 = h2.z * dv; hs.z = f2bf_rne(hv2); ag.z = hv2 * dv + bb.z;
    float hv3 = h2.w * dv; hs.w = f2bf_rne(hv3); ag.w = hv3 * dv + bb.w;
    size_t o = ((size_t)node << 4) + (l << 2);
    *(ushort4*)(hh2_bf + o) = hs;
    *(f32x4*)(aggs2 + o) = ag;
}

// ---------------------------------------------------------------------------
// K5: pull2 + log_softmax fused. Same 4-lane gather structure.
__global__ __launch_bounds__(256) void pull2_kernel(const unsigned short* __restrict__ hh2_bf,
                                                    const float* __restrict__ aggs2,
                                                    const float* __restrict__ dinv,
                                                    const int* __restrict__ row,
                                                    const int* __restrict__ rowe,
                                                    const int* __restrict__ csr,
                                                    float* __restrict__ out) {
    int t = blockIdx.x * 256 + threadIdx.x;
    int node = t >> 2;
    int l = t & 3;
    if (node >= N_NODES) return;

    int p = row[node], e = rowe[node];
    const unsigned short* hb = hh2_bf + (l << 2);
    f32x4 a0 = {0,0,0,0}, a1 = {0,0,0,0}, a2 = {0,0,0,0}, a3 = {0,0,0,0};
    for (; p < e; p += 4) {
        int4 s = *(const int4*)(csr + p);
        ushort4 g0 = *(const ushort4*)(hb + (s.x << 4));
        ushort4 g1 = *(const ushort4*)(hb + (s.y << 4));
        ushort4 g2 = *(const ushort4*)(hb + (s.z << 4));
        ushort4 g3 = *(const ushort4*)(hb + (s.w << 4));
        a0.x += bf2f(g0.x); a0.y += bf2f(g0.y); a0.z += bf2f(g0.z); a0.w += bf2f(g0.w);
        a1.x += bf2f(g1.x); a1.y += bf2f(g1.y); a1.z += bf2f(g1.z); a1.w += bf2f(g1.w);
        a2.x += bf2f(g2.x); a2.y += bf2f(g2.y); a2.z += bf2f(g2.z); a2.w += bf2f(g2.w);
        a3.x += bf2f(g3.x); a3.y += bf2f(g3.y); a3.z += bf2f(g3.z); a3.w += bf2f(g3.w);
    }
    f32x4 a = (a0 + a1) + (a2 + a3);
    float dv = dinv[node];
    f32x4 base = *(const f32x4*)(aggs2 + ((size_t)node << 4) + (l << 2));
    f32x4 o4;
    o4.x = base.x + dv * a.x; o4.y = base.y + dv * a.y;
    o4.z = base.z + dv * a.z; o4.w = base.w + dv * a.w;

    // log_softmax over the 16 features spread across the 4-lane group
    float m = fmaxf(fmaxf(o4.x, o4.y), fmaxf(o4.z, o4.w));
    m = fmaxf(m, __shfl_xor(m, 1));
    m = fmaxf(m, __shfl_xor(m, 2));
    float s = expf(o4.x - m) + expf(o4.y - m) + expf(o4.z - m) + expf(o4.w - m);
    s += __shfl_xor(s, 1);
    s += __shfl_xor(s, 2);
    float ls = m + logf(s);
    f32x4 r;
    r.x = o4.x - ls; r.y = o4.y - ls; r.z = o4.z - ls; r.w = o4.w - ls;
    *(f32x4*)(out + ((size_t)node << 4) + (l << 2)) = r;
}

// ---------------------------------------------------------------------------
extern "C" void kernel_launch(void* const* d_in, const int* in_sizes, int n_in,
                              void* d_out, int out_size, void* d_ws, size_t ws_size,
                              hipStream_t stream) {
    const float* x    = (const float*)d_in[0];
    const float* W1   = (const float*)d_in[1];
    const float* b1   = (const float*)d_in[2];
    const float* W2   = (const float*)d_in[3];
    const float* b2   = (const float*)d_in[4];
    const int*   ei   = (const int*)d_in[5];
    const int*   src  = ei;             // edge_index[0]
    const int*   dst  = ei + N_EDGES;   // edge_index[1]
    float* out = (float*)d_out;

    // workspace layout (4-byte words); total ~36.5 MB
    constexpr size_t SLOTS    = (size_t)NBKT * CAP;          // 4,003,840
    constexpr size_t OFF_DINV = 512;
    constexpr size_t OFF_ROW  = 512 + (size_t)NPAD;
    constexpr size_t OFF_ROWE = 512 + 2 * (size_t)NPAD;
    constexpr size_t OFF_CSR  = 512 + 3 * (size_t)NPAD;
    constexpr size_t OFF_HH   = OFF_CSR + SLOTS;             // (N+1)*16 bf16
    constexpr size_t OFF_AG1  = OFF_HH + 800512;
    constexpr size_t OFF_HH2  = OFF_AG1 + 1600000;
    constexpr size_t OFF_AG2  = OFF_HH2 + 800512;
    constexpr size_t OFF_W1T  = OFF_AG2 + 1600000;

    int*   wsi  = (int*)d_ws;
    float* wsf  = (float*)d_ws;
    int*   gcur  = wsi;
    float* dinv  = wsf + OFF_DINV;
    int*   row   = wsi + OFF_ROW;
    int*   rowe  = wsi + OFF_ROWE;
    int*   csr   = wsi + OFF_CSR;
    unsigned int* binned = (unsigned int*)csr;   // shared: staged per-bucket in LDS
    unsigned short* hh_bf  = (unsigned short*)(wsi + OFF_HH);
    float*          aggs1  = wsf + OFF_AG1;
    unsigned short* hh2_bf = (unsigned short*)(wsi + OFF_HH2);
    float*          aggs2  = wsf + OFF_AG2;
    unsigned short* w1t    = (unsigned short*)(wsi + OFF_W1T);

    const int MB  = (N_NODES + 63) / 64;         // 1563 (MFMA gemm blocks)
    const int GB4 = (N_NODES * 4 + 255) / 256;   // 1563 (pull blocks, 4 lanes/node)

    prep_kernel       <<<32, 256, 0, stream>>>(W1, w1t, gcur, hh_bf, hh2_bf);
    bin_scatter_kernel<<<SBLK, 1024, 0, stream>>>(src, dst, gcur, binned);
    csr_bucket_kernel <<<NBKT, 1024, 0, stream>>>(binned, gcur, row, rowe, csr, dinv);
    gemm1_kernel      <<<MB, 256, 0, stream>>>(x, w1t, b1, dinv, hh_bf, aggs1);
    pull1_kernel      <<<GB4, 256, 0, stream>>>(hh_bf, aggs1, dinv, row, rowe, csr, W2, b2, hh2_bf, aggs2);
    pull2_kernel      <<<GB4, 256, 0, stream>>>(hh2_bf, aggs2, dinv, row, rowe, csr, out);
}